// Round 4
// baseline (933.279 us; speedup 1.0000x reference)
//
#include <hip/hip_runtime.h>
#include <cmath>

// ---- problem dims (fixed per reference) ----
#define YCH 8        // y_channels
#define NTR 16       // trials
#define LLEN 4096    // trial length
#define CK  16       // kernels per channel
#define KS  64       // kernel size
#define ENC 4033     // LLEN - KS + 1
#define NP  128      // YCH*NTR independent problems
#define INV_LIP 0.1f     // 1/10
#define THRESH 0.01f     // LAM/LIP = 0.1/10

#define XW4 272          // float4s staged per tile window (1088 floats)
#define XPITCH 1104      // LDS pitch in floats (4416 B, 16B-aligned)

// B over [gi4, gi4+3], zero outside [0, ENC):  B = a + gamma*(a - p)
__device__ __forceinline__ float4 loadB4(const float* __restrict__ A,
                                         const float* __restrict__ P,
                                         float gamma, size_t coff, int gi4)
{
    if (gi4 >= 0 && gi4 + 3 < ENC) {
        float4 a = *(const float4*)(A + coff + gi4);
        float4 p = *(const float4*)(P + coff + gi4);
        return make_float4(fmaf(gamma, a.x - p.x, a.x),
                           fmaf(gamma, a.y - p.y, a.y),
                           fmaf(gamma, a.z - p.z, a.z),
                           fmaf(gamma, a.w - p.w, a.w));
    }
    float r[4];
    #pragma unroll
    for (int j = 0; j < 4; ++j) {
        int gi = gi4 + j;
        if (gi >= 0 && gi < ENC) {
            float a = A[coff + gi], p = P[coff + gi];
            r[j] = fmaf(gamma, a - p, a);
        } else r[j] = 0.f;
    }
    return make_float4(r[0], r[1], r[2], r[3]);
}

// float4 from a length-LLEN row, zero-padded past the end (gi4 >= 0)
__device__ __forceinline__ float4 loadR4(const float* __restrict__ base, int gi4)
{
    if (gi4 + 3 < LLEN) return *(const float4*)(base + gi4);
    float r[4];
    #pragma unroll
    for (int j = 0; j < 4; ++j)
        r[j] = (gi4 + j < LLEN) ? base[gi4 + j] : 0.f;
    return make_float4(r[0], r[1], r[2], r[3]);
}

// =====================================================================
// resid_partial<NC>: part[q][p][t] = sum_{c in quad q, k} B[p,c,t-k]*H[ch,c,k]
// block = (ttile, q, p), 256 thr, 4 outputs/thread, B formed on the fly.
// =====================================================================
template<int NC>
__global__ __launch_bounds__(256) void resid_partial(
    const float* __restrict__ H,
    const float* __restrict__ Acur, const float* __restrict__ Aprev,
    float gamma, float* __restrict__ part)
{
    __shared__ __align__(16) float xs[2][XPITCH];
    __shared__ __align__(16) float hs[NC * KS];
    const int tid = threadIdx.x;
    const int t0  = blockIdx.x * 1024;
    const int c0  = blockIdx.y * NC;
    const int p   = blockIdx.z;
    const int ch  = p >> 4;

    for (int i = tid; i < NC * 16; i += 256)
        ((float4*)hs)[i] = ((const float4*)(H + ((size_t)ch * CK + c0) * KS))[i];

    const size_t pbase = (size_t)p * CK * ENC;

    ((float4*)xs[0])[tid] =
        loadB4(Acur, Aprev, gamma, pbase + (size_t)c0 * ENC, t0 - 64 + 4 * tid);
    if (tid + 256 < XW4)
        ((float4*)xs[0])[tid + 256] =
            loadB4(Acur, Aprev, gamma, pbase + (size_t)c0 * ENC, t0 - 64 + 4 * (tid + 256));
    __syncthreads();

    float acc[4] = {0.f, 0.f, 0.f, 0.f};

    for (int cc = 0; cc < NC; ++cc) {
        // prefetch next channel (global -> regs), hidden under compute
        float4 pf0 = make_float4(0,0,0,0), pf1 = make_float4(0,0,0,0);
        bool have1 = false;
        if (cc + 1 < NC) {
            size_t coff = pbase + (size_t)(c0 + cc + 1) * ENC;
            pf0 = loadB4(Acur, Aprev, gamma, coff, t0 - 64 + 4 * tid);
            if (tid + 256 < XW4) {
                pf1 = loadB4(Acur, Aprev, gamma, coff, t0 - 64 + 4 * (tid + 256));
                have1 = true;
            }
        }

        // register window xs[4*tid .. 4*tid+67]; output t = t0+4*tid+j
        float wf[68];
        const float4* xr = (const float4*)(xs[cc & 1]) + tid;
        #pragma unroll
        for (int q = 0; q < 17; ++q) {
            float4 t4 = xr[q];
            wf[4*q] = t4.x; wf[4*q+1] = t4.y; wf[4*q+2] = t4.z; wf[4*q+3] = t4.w;
        }
        const float4* hc = (const float4*)(hs + cc * KS);
        #pragma unroll
        for (int g = 0; g < 16; ++g) {
            float4 h4 = hc[g];
            float hh[4] = {h4.x, h4.y, h4.z, h4.w};
            #pragma unroll
            for (int m = 0; m < 4; ++m) {
                const int k = 4 * g + m;          // tap index
                #pragma unroll
                for (int j = 0; j < 4; ++j)       // local idx = 64 + j - k
                    acc[j] = fmaf(wf[64 + j - k], hh[m], acc[j]);
            }
        }

        if (cc + 1 < NC) {
            ((float4*)xs[(cc + 1) & 1])[tid] = pf0;
            if (have1) ((float4*)xs[(cc + 1) & 1])[tid + 256] = pf1;
            __syncthreads();
        }
    }

    const int t = t0 + 4 * tid;
    *(float4*)(part + ((size_t)blockIdx.y * NP + p) * LLEN + t) =
        make_float4(acc[0], acc[1], acc[2], acc[3]);
}

// =====================================================================
// reduce<NQ>: res[p][t] = y[n,ch,t] - sum_q part[q][p][t]
// grid (8, NP) x 128 thr, one float4 per thread.
// =====================================================================
template<int NQ>
__global__ __launch_bounds__(128) void reduce_kernel(
    const float* __restrict__ y, const float* __restrict__ part,
    float* __restrict__ res)
{
    const int p = blockIdx.y;
    const int t = blockIdx.x * 512 + 4 * threadIdx.x;
    const int n = p & 15, ch = p >> 4;
    float4 s = *(const float4*)(y + ((size_t)n * YCH + ch) * LLEN + t);
    #pragma unroll
    for (int q = 0; q < NQ; ++q) {
        float4 v = *(const float4*)(part + ((size_t)q * NP + p) * LLEN + t);
        s.x -= v.x; s.y -= v.y; s.z -= v.z; s.w -= v.w;
    }
    *(float4*)(res + (size_t)p * LLEN + t) = s;
}

// =====================================================================
// fista_quad: block = (ttile, cquad, p); 4 output channels per block.
//   g[c,i] = sum_k rs[i+k]*H[ch,c,k];  x_new = relu(B + g/LIP - thr)
// =====================================================================
__global__ __launch_bounds__(256) void fista_quad(
    const float* __restrict__ rsrc, int rsrc_is_y,
    const float* __restrict__ H,
    const float* __restrict__ Acur, const float* __restrict__ Aprev,
    float gamma, int first, float* __restrict__ Anext)
{
    __shared__ __align__(16) float rs[XPITCH];
    __shared__ __align__(16) float hs[4 * KS];
    const int tid = threadIdx.x;
    const int i0  = blockIdx.x * 1024;
    const int c0  = blockIdx.y * 4;
    const int p   = blockIdx.z;
    const int n = p & 15, ch = p >> 4;

    if (tid < 64)
        ((float4*)hs)[tid] = ((const float4*)(H + ((size_t)ch * CK + c0) * KS))[tid];

    const float* rbase = rsrc + (rsrc_is_y ? ((size_t)n * YCH + ch) * LLEN
                                           : (size_t)p * LLEN);
    ((float4*)rs)[tid] = loadR4(rbase, i0 + 4 * tid);
    if (tid + 256 < XW4)
        ((float4*)rs)[tid + 256] = loadR4(rbase, i0 + 4 * (tid + 256));
    __syncthreads();

    // hoisted register window rs[4*tid .. 4*tid+67], shared by 4 channels
    float wf[68];
    const float4* rr = (const float4*)rs + tid;
    #pragma unroll
    for (int q = 0; q < 17; ++q) {
        float4 t4 = rr[q];
        wf[4*q] = t4.x; wf[4*q+1] = t4.y; wf[4*q+2] = t4.z; wf[4*q+3] = t4.w;
    }

    const int i = i0 + 4 * tid;
    const size_t pb = (size_t)p * CK * ENC;
    const bool vec = (i + 3 < ENC);

    float4 a0 = make_float4(0,0,0,0), p0 = make_float4(0,0,0,0);
    if (!first && vec) {
        a0 = *(const float4*)(Acur  + pb + (size_t)c0 * ENC + i);
        p0 = *(const float4*)(Aprev + pb + (size_t)c0 * ENC + i);
    }

    for (int cc = 0; cc < 4; ++cc) {
        float4 a1 = make_float4(0,0,0,0), p1 = make_float4(0,0,0,0);
        if (!first && vec && cc < 3) {
            a1 = *(const float4*)(Acur  + pb + (size_t)(c0 + cc + 1) * ENC + i);
            p1 = *(const float4*)(Aprev + pb + (size_t)(c0 + cc + 1) * ENC + i);
        }

        float acc[4] = {0.f, 0.f, 0.f, 0.f};
        const float4* hc = (const float4*)(hs + cc * KS);
        #pragma unroll
        for (int g = 0; g < 16; ++g) {
            float4 h4 = hc[g];
            float hh[4] = {h4.x, h4.y, h4.z, h4.w};
            #pragma unroll
            for (int m = 0; m < 4; ++m) {
                const int k = 4 * g + m;
                #pragma unroll
                for (int j = 0; j < 4; ++j)
                    acc[j] = fmaf(wf[k + j], hh[m], acc[j]);
            }
        }

        const size_t idx = pb + (size_t)(c0 + cc) * ENC + i;
        if (vec) {
            float B[4] = {0.f, 0.f, 0.f, 0.f};
            if (!first) {
                float av[4] = {a0.x, a0.y, a0.z, a0.w};
                float pv[4] = {p0.x, p0.y, p0.z, p0.w};
                #pragma unroll
                for (int j = 0; j < 4; ++j) B[j] = fmaf(gamma, av[j] - pv[j], av[j]);
            }
            float4 o;
            o.x = fmaxf(fmaf(acc[0], INV_LIP, B[0]) - THRESH, 0.f);
            o.y = fmaxf(fmaf(acc[1], INV_LIP, B[1]) - THRESH, 0.f);
            o.z = fmaxf(fmaf(acc[2], INV_LIP, B[2]) - THRESH, 0.f);
            o.w = fmaxf(fmaf(acc[3], INV_LIP, B[3]) - THRESH, 0.f);
            *(float4*)(Anext + idx) = o;
        } else if (i < ENC) {
            #pragma unroll
            for (int j = 0; j < 4; ++j) {
                if (i + j < ENC) {
                    float B = 0.f;
                    if (!first) {
                        float a = Acur[idx + j], pp = Aprev[idx + j];
                        B = fmaf(gamma, a - pp, a);
                    }
                    Anext[idx + j] = fmaxf(fmaf(acc[j], INV_LIP, B) - THRESH, 0.f);
                }
            }
        }
        a0 = a1; p0 = p1;
    }
}

// =====================================================================
extern "C" void kernel_launch(void* const* d_in, const int* in_sizes, int n_in,
                              void* d_out, int out_size, void* d_ws, size_t ws_size,
                              hipStream_t stream)
{
    const float* y = (const float*)d_in[0];   // [NTR, YCH, LLEN]
    const float* H = (const float*)d_in[1];   // [YCH, CK, 1, KS]
    const size_t XSZ = (size_t)NP * CK * ENC; // 8,259,584 floats
    const size_t RSZ = (size_t)NP * LLEN;     //   524,288 floats

    float* bufA = (float*)d_ws;               // A_t for even t
    float* bufB = (float*)d_out;              // A_t for odd t (A9 -> d_out)
    float* res  = bufA + XSZ;
    float* part = res + RSZ;

    // pick channel-split width by available workspace (deterministic)
    const size_t haveF = ws_size / sizeof(float);
    int mode;                                  // number of partial arrays
    if      (haveF >= XSZ + RSZ + 4 * RSZ) mode = 4;
    else if (haveF >= XSZ + RSZ + 2 * RSZ) mode = 2;
    else                                   mode = 1;

    double s[11]; s[0] = 1.0;
    for (int t = 1; t <= 10; ++t) s[t] = 0.5 * (1.0 + sqrt(1.0 + 4.0 * s[t-1] * s[t-1]));

    dim3 gF(4, 4, NP);

    for (int t = 0; t < 10; ++t) {
        float gamma = (t == 0) ? 0.f : (float)((s[t-1] - 1.0) / s[t]);
        float* Anext       = (t & 1) ? bufB : bufA;
        const float* Acur  = (t & 1) ? bufA : bufB;            // A_{t-1}
        const float* Aprev = (t <= 1) ? Acur                   // gamma==0, unused
                                      : ((t & 1) ? bufB : bufA); // A_{t-2}
        if (t == 0) {
            // B_0 = 0 => res = y; fuse into update kernel
            fista_quad<<<gF, 256, 0, stream>>>(y, 1, H, bufA, bufA, 0.f, 1, bufA);
        } else {
            if (mode == 4) {
                resid_partial<4><<<dim3(4, 4, NP), 256, 0, stream>>>(H, Acur, Aprev, gamma, part);
                reduce_kernel<4><<<dim3(8, NP), 128, 0, stream>>>(y, part, res);
            } else if (mode == 2) {
                resid_partial<8><<<dim3(4, 2, NP), 256, 0, stream>>>(H, Acur, Aprev, gamma, part);
                reduce_kernel<2><<<dim3(8, NP), 128, 0, stream>>>(y, part, res);
            } else {
                resid_partial<16><<<dim3(4, 1, NP), 256, 0, stream>>>(H, Acur, Aprev, gamma, part);
                reduce_kernel<1><<<dim3(8, NP), 128, 0, stream>>>(y, part, res);
            }
            fista_quad<<<gF, 256, 0, stream>>>(res, 0, H, Acur, Aprev, gamma, 0, Anext);
        }
    }
}

// Round 5
// 913.505 us; speedup vs baseline: 1.0216x; 1.0216x over previous
//
#include <hip/hip_runtime.h>
#include <cmath>

// ---- problem dims (fixed per reference) ----
#define YCH 8        // y_channels
#define NTR 16       // trials
#define LLEN 4096    // trial length
#define CK  16       // kernels per channel
#define KS  64       // kernel size
#define ENC 4033     // LLEN - KS + 1
#define NP  128      // YCH*NTR independent problems
#define INV_LIP 0.1f     // 1/10
#define THRESH 0.01f     // LAM/LIP = 0.1/10

#define XW4 272          // float4s staged per fista tile window (1088 floats)

// B over [gi4, gi4+3], zero outside [0, ENC):  B = a + gamma*(a - p)
__device__ __forceinline__ float4 loadB4(const float* __restrict__ A,
                                         const float* __restrict__ P,
                                         float gamma, size_t coff, int gi4)
{
    if (gi4 >= 0 && gi4 + 3 < ENC) {
        float4 a = *(const float4*)(A + coff + gi4);
        float4 p = *(const float4*)(P + coff + gi4);
        return make_float4(fmaf(gamma, a.x - p.x, a.x),
                           fmaf(gamma, a.y - p.y, a.y),
                           fmaf(gamma, a.z - p.z, a.z),
                           fmaf(gamma, a.w - p.w, a.w));
    }
    float r[4];
    #pragma unroll
    for (int j = 0; j < 4; ++j) {
        int gi = gi4 + j;
        if (gi >= 0 && gi < ENC) {
            float a = A[coff + gi], p = P[coff + gi];
            r[j] = fmaf(gamma, a - p, a);
        } else r[j] = 0.f;
    }
    return make_float4(r[0], r[1], r[2], r[3]);
}

// =====================================================================
// resid_partial4: part[q][p][t] = sum_{c in quad q, k} B[p,c,t-k]*H[ch,c,k]
// block = (thalf, q, p), 256 thr (4 waves), 8 outputs/lane.
// NO LDS data staging, NO inner barriers: each lane's 72-float window is
// loaded straight from global (L1-served, 9x lane overlap), momentum in-reg.
// Only H is staged in LDS (broadcast reads, conflict-free).
// =====================================================================
__global__ __launch_bounds__(256, 4) void resid_partial4(
    const float* __restrict__ H,
    const float* __restrict__ Acur, const float* __restrict__ Aprev,
    float gamma, float* __restrict__ part)
{
    __shared__ __align__(16) float hs[4 * KS];
    const int tid = threadIdx.x;
    const int c0  = blockIdx.y * 4;
    const int p   = blockIdx.z;
    const int ch  = p >> 4;

    if (tid < 64)
        ((float4*)hs)[tid] = ((const float4*)(H + ((size_t)ch * CK + c0) * KS))[tid];
    __syncthreads();

    const int lane = tid & 63;
    const int wv   = tid >> 6;
    const int tb   = blockIdx.x * 2048 + wv * 512 + lane * 8;  // 8 outputs [tb, tb+8)
    const size_t pbase = (size_t)p * CK * ENC;

    float acc[8] = {0.f,0.f,0.f,0.f,0.f,0.f,0.f,0.f};

    for (int cc = 0; cc < 4; ++cc) {
        const size_t coff = pbase + (size_t)(c0 + cc) * ENC;
        // register window: B[tb-64 .. tb+8)  (72 floats, 18 guarded float4)
        float w[72];
        #pragma unroll
        for (int q = 0; q < 18; ++q) {
            float4 v = loadB4(Acur, Aprev, gamma, coff, tb - 64 + 4 * q);
            w[4*q] = v.x; w[4*q+1] = v.y; w[4*q+2] = v.z; w[4*q+3] = v.w;
        }
        const float4* hc = (const float4*)(hs + cc * KS);
        #pragma unroll
        for (int g = 0; g < 16; ++g) {
            float4 h4 = hc[g];
            float hh[4] = {h4.x, h4.y, h4.z, h4.w};
            #pragma unroll
            for (int m = 0; m < 4; ++m) {
                const int k = 4 * g + m;           // tap index
                #pragma unroll
                for (int j = 0; j < 8; ++j)        // window idx = 64 + j - k
                    acc[j] = fmaf(w[64 + j - k], hh[m], acc[j]);
            }
        }
    }

    float* dst = part + ((size_t)blockIdx.y * NP + p) * LLEN + tb;
    *(float4*)(dst)     = make_float4(acc[0], acc[1], acc[2], acc[3]);
    *(float4*)(dst + 4) = make_float4(acc[4], acc[5], acc[6], acc[7]);
}

// =====================================================================
// fista_quad: block = (itile, cquad, p); 4 output channels per block.
//   staging: rs = y - sum_q part[q]   (reduce fused here; first: rs = y)
//   g[c,i] = sum_k rs[i+k]*H[ch,c,k];  x_new = relu(B + g/LIP - thr)
// One barrier total; window hoisted to registers across the 4 channels.
// =====================================================================
__global__ __launch_bounds__(256) void fista_quad(
    const float* __restrict__ y, const float* __restrict__ part,
    const float* __restrict__ H,
    const float* __restrict__ Acur, const float* __restrict__ Aprev,
    float gamma, int first, float* __restrict__ Anext)
{
    __shared__ __align__(16) float rs[XW4 * 4];
    __shared__ __align__(16) float hs[4 * KS];
    const int tid = threadIdx.x;
    const int i0  = blockIdx.x * 1024;
    const int c0  = blockIdx.y * 4;
    const int p   = blockIdx.z;
    const int n = p & 15, ch = p >> 4;

    if (tid < 64)
        ((float4*)hs)[tid] = ((const float4*)(H + ((size_t)ch * CK + c0) * KS))[tid];

    const float* ybase = y + ((size_t)n * YCH + ch) * LLEN;
    #pragma unroll
    for (int s = 0; s < 2; ++s) {
        int l4 = tid + 256 * s;
        if (l4 < XW4) {
            int gi4 = i0 + 4 * l4;
            float4 v;
            if (gi4 + 3 < LLEN) {
                v = *(const float4*)(ybase + gi4);
                if (!first) {
                    #pragma unroll
                    for (int q = 0; q < 4; ++q) {
                        float4 pv = *(const float4*)(part + ((size_t)q * NP + p) * LLEN + gi4);
                        v.x -= pv.x; v.y -= pv.y; v.z -= pv.z; v.w -= pv.w;
                    }
                }
            } else {
                float r[4];
                #pragma unroll
                for (int j = 0; j < 4; ++j) {
                    int gi = gi4 + j;
                    if (gi < LLEN) {
                        float t = ybase[gi];
                        if (!first) {
                            #pragma unroll
                            for (int q = 0; q < 4; ++q)
                                t -= part[((size_t)q * NP + p) * LLEN + gi];
                        }
                        r[j] = t;
                    } else r[j] = 0.f;
                }
                v = make_float4(r[0], r[1], r[2], r[3]);
            }
            ((float4*)rs)[l4] = v;
        }
    }
    __syncthreads();

    // hoisted register window rs[4*tid .. 4*tid+67], shared by 4 channels
    float wf[68];
    const float4* rr = (const float4*)rs + tid;
    #pragma unroll
    for (int q = 0; q < 17; ++q) {
        float4 t4 = rr[q];
        wf[4*q] = t4.x; wf[4*q+1] = t4.y; wf[4*q+2] = t4.z; wf[4*q+3] = t4.w;
    }

    const int i = i0 + 4 * tid;
    const size_t pb = (size_t)p * CK * ENC;
    const bool vec = (i + 3 < ENC);

    float4 a0 = make_float4(0,0,0,0), p0 = make_float4(0,0,0,0);
    if (!first && vec) {
        a0 = *(const float4*)(Acur  + pb + (size_t)c0 * ENC + i);
        p0 = *(const float4*)(Aprev + pb + (size_t)c0 * ENC + i);
    }

    for (int cc = 0; cc < 4; ++cc) {
        float4 a1 = make_float4(0,0,0,0), p1 = make_float4(0,0,0,0);
        if (!first && vec && cc < 3) {
            a1 = *(const float4*)(Acur  + pb + (size_t)(c0 + cc + 1) * ENC + i);
            p1 = *(const float4*)(Aprev + pb + (size_t)(c0 + cc + 1) * ENC + i);
        }

        float acc[4] = {0.f, 0.f, 0.f, 0.f};
        const float4* hc = (const float4*)(hs + cc * KS);
        #pragma unroll
        for (int g = 0; g < 16; ++g) {
            float4 h4 = hc[g];
            float hh[4] = {h4.x, h4.y, h4.z, h4.w};
            #pragma unroll
            for (int m = 0; m < 4; ++m) {
                const int k = 4 * g + m;
                #pragma unroll
                for (int j = 0; j < 4; ++j)
                    acc[j] = fmaf(wf[k + j], hh[m], acc[j]);
            }
        }

        const size_t idx = pb + (size_t)(c0 + cc) * ENC + i;
        if (vec) {
            float B[4] = {0.f, 0.f, 0.f, 0.f};
            if (!first) {
                float av[4] = {a0.x, a0.y, a0.z, a0.w};
                float pv[4] = {p0.x, p0.y, p0.z, p0.w};
                #pragma unroll
                for (int j = 0; j < 4; ++j) B[j] = fmaf(gamma, av[j] - pv[j], av[j]);
            }
            float4 o;
            o.x = fmaxf(fmaf(acc[0], INV_LIP, B[0]) - THRESH, 0.f);
            o.y = fmaxf(fmaf(acc[1], INV_LIP, B[1]) - THRESH, 0.f);
            o.z = fmaxf(fmaf(acc[2], INV_LIP, B[2]) - THRESH, 0.f);
            o.w = fmaxf(fmaf(acc[3], INV_LIP, B[3]) - THRESH, 0.f);
            *(float4*)(Anext + idx) = o;
        } else if (i < ENC) {
            #pragma unroll
            for (int j = 0; j < 4; ++j) {
                if (i + j < ENC) {
                    float B = 0.f;
                    if (!first) {
                        float a = Acur[idx + j], pp = Aprev[idx + j];
                        B = fmaf(gamma, a - pp, a);
                    }
                    Anext[idx + j] = fmaxf(fmaf(acc[j], INV_LIP, B) - THRESH, 0.f);
                }
            }
        }
        a0 = a1; p0 = p1;
    }
}

// =====================================================================
extern "C" void kernel_launch(void* const* d_in, const int* in_sizes, int n_in,
                              void* d_out, int out_size, void* d_ws, size_t ws_size,
                              hipStream_t stream)
{
    const float* y = (const float*)d_in[0];   // [NTR, YCH, LLEN]
    const float* H = (const float*)d_in[1];   // [YCH, CK, 1, KS]
    const size_t XSZ = (size_t)NP * CK * ENC; // 8,259,584 floats

    float* bufA = (float*)d_ws;               // A_t for even t
    float* bufB = (float*)d_out;              // A_t for odd t (A9 -> d_out)
    float* part = bufA + XSZ;                 // [4][NP][LLEN] partial synth sums

    double s[11]; s[0] = 1.0;
    for (int t = 1; t <= 10; ++t) s[t] = 0.5 * (1.0 + sqrt(1.0 + 4.0 * s[t-1] * s[t-1]));

    dim3 gR(2, 4, NP), gF(4, 4, NP);

    for (int t = 0; t < 10; ++t) {
        float gamma = (t == 0) ? 0.f : (float)((s[t-1] - 1.0) / s[t]);
        float* Anext       = (t & 1) ? bufB : bufA;
        const float* Acur  = (t & 1) ? bufA : bufB;            // A_{t-1}
        const float* Aprev = (t <= 1) ? Acur                   // gamma==0, value unused
                                      : ((t & 1) ? bufB : bufA); // A_{t-2}
        if (t == 0) {
            // B_0 = 0 => res = y; fuse into update kernel (first=1)
            fista_quad<<<gF, 256, 0, stream>>>(y, part, H, bufA, bufA, 0.f, 1, bufA);
        } else {
            resid_partial4<<<gR, 256, 0, stream>>>(H, Acur, Aprev, gamma, part);
            fista_quad<<<gF, 256, 0, stream>>>(y, part, H, Acur, Aprev, gamma, 0, Anext);
        }
    }
}